// Round 19
// baseline (235.731 us; speedup 1.0000x reference)
//
#include <hip/hip_runtime.h>
#include <math.h>
#include <stdint.h>

typedef _Float16 f16;
typedef _Float16 f16x8 __attribute__((ext_vector_type(8)));
typedef float f32x4 __attribute__((ext_vector_type(4)));

#define KCODES 8192
#define DDIM   256
#define NTOT   16384
#define QT     32      // queries per block; grid 512 = 2 lockstep generations at 1 block/CU
#define NKT    32      // k-tiles of 256 codes
#define NCH    256     // total 32KB chunks = NKT*8
#define CHB    32768   // chunk image bytes: 2 planes * 256 codes * 32 d * 2B

#define F16_MIN_NORMAL 6.103515625e-05f

// ws layout: [0] loss | +256B e2[8192] f32 | z2[16384] f32 | +131072B emb-plane image (8 MB)

// z2[n]: exact (fp64) sum of fp32 squares, rounded once (rounds 2-18 verified). Also zeroes loss.
__global__ void z2_kernel(const float* __restrict__ z, float* __restrict__ z2out,
                          float* __restrict__ loss) {
    int n  = blockIdx.x * 256 + threadIdx.x;
    if (n == 0) loss[0] = 0.0f;
    int b  = n >> 10;
    int hw = n & 1023;
    const float* base = z + (size_t)b * DDIM * 1024 + hw;
    double acc = 0.0;
    #pragma unroll 8
    for (int d = 0; d < 256; ++d) {
        float v  = base[(size_t)d * 1024];
        float sq = __fmul_rn(v, v);
        acc += (double)sq;
    }
    z2out[n] = (float)acc;
}

// split emb into 2 fp16 planes (pre-scaled by 2^13) as the swizzled image; fused e2.
// Image layout bit-identical to rounds 3-18.
__global__ void esplit_kernel(const float* __restrict__ emb, char* __restrict__ img,
                              float* __restrict__ e2out) {
    __shared__ double part[4];
    int c = blockIdx.x, d = threadIdx.x;
    float ev = emb[(size_t)c * 256 + d];
    double sq = (double)__fmul_rn(ev, ev);
    #pragma unroll
    for (int off = 32; off > 0; off >>= 1) sq += __shfl_down(sq, off, 64);
    if ((d & 63) == 0) part[d >> 6] = sq;
    __syncthreads();
    if (d == 0) e2out[c] = (float)(part[0] + part[1] + part[2] + part[3]);
    float e = ev * 8192.0f;                               // exact pow2 scale
    float eh = 0.0f;
    if (fabsf(e) >= F16_MIN_NORMAL) eh = (float)(f16)e;   // normal-or-zero hi plane
    f16 ehh = (f16)eh;
    f16 emm = (f16)((e - eh) * 2048.0f);                  // residual scaled 2^11
    int kt = c >> 8, ch = d >> 5, ci = c & 255, dp = d & 31;
    char* p = img + (size_t)(kt * 8 + ch) * CHB;
    int off2 = (ci * 64 + dp * 2) ^ ((ci & 7) << 4);      // XOR swizzle (bits 4-6)
    *(f16*)(p + off2) = ehh;
    *(f16*)(p + 16384 + off2) = emm;
}

// 32-bit LDS offset of a __shared__-derived pointer (generic -> AS(3) cast)
__device__ __forceinline__ uint32_t lds_a(const void* p) {
    return (uint32_t)(uintptr_t)(const __attribute__((address_space(3))) char*)p;
}
// inline-asm ds_read_b128 with NO waitcnt: caller manages lgkmcnt (counted-wait pipeline)
__device__ __forceinline__ f16x8 ds_read_b128_nowait(uint32_t addr) {
    f32x4 r;
    asm volatile("ds_read_b128 %0, %1" : "=v"(r) : "v"(addr));
    return __builtin_bit_cast(f16x8, r);
}

// EXACT R13 structure (QT=32, 8 waves, A+B register double-buffers, T15 score spreading,
// pacing barrier every 2 k-tiles) + FORCED A-prefetch distance: A ds_reads are inline-asm
// (fixed program order), each phase waits lgkmcnt(4) — draining only LAST phase's reads
// while THIS phase's 4 stay in flight — then sched_barrier(0) fences keep the MFMA
// cluster between the waits (guide rule #18). R13/R18 counters (MfmaUtil=45% = exactly
// the serial [read|MFMA] split) indicate the compiler had collapsed the prefetch distance.
__launch_bounds__(512, 2)
__global__ void vq_main(const float* __restrict__ z, const float* __restrict__ emb,
                        const float* __restrict__ e2w, const float* __restrict__ z2w,
                        const char* __restrict__ img, float* __restrict__ loss_accum,
                        float* __restrict__ out0, float* __restrict__ out1) {
    // 41 KB per plane (only first 16 KB used) -> 86 KB/block -> 1 block/CU occupancy cap
    __shared__ __align__(16) char zsH[41984];     // z hi plane  [32 q][256 d] f16, swizzled
    __shared__ __align__(16) char zsM[41984];     // z mid plane (scaled 2^11)
    __shared__ float redv[8][QT];
    __shared__ int   redi[8][QT];
    __shared__ int   bidx[QT];
    __shared__ float wsum[8];

    const int tid  = threadIdx.x;
    const int w    = tid >> 6;
    const int lane = tid & 63;
    const int l15  = lane & 15;
    const int lg   = lane >> 4;
    const int nb   = blockIdx.x * QT;
    const int b    = nb >> 10;
    const int hw0  = nb & 1023;

    // per-lane B read offsets (fixed per chunk; same formula as rounds 3-18)
    int boff[2];
    #pragma unroll
    for (int n = 0; n < 2; ++n) {
        const int c = w * 32 + n * 16 + l15;
        boff[n] = (c * 64 + lg * 16) ^ ((c & 7) << 4);
    }
    // precomputed A-LDS offsets per (ch, m)
    int aoffs[8][2];
    #pragma unroll
    for (int ch = 0; ch < 8; ++ch)
        #pragma unroll
        for (int m = 0; m < 2; ++m) {
            const int q = m * 16 + l15;
            aoffs[ch][m] = (q * 512 + (ch * 32 + lg * 8) * 2) ^ ((q & 7) << 4);
        }

    // ---- build z fp16 planes in LDS (b128 writes; values/offsets bit-identical) ----
    {
        const int q = tid & 31, dg = tid >> 5;    // dg 0..15 -> 16 d per thread
        #pragma unroll
        for (int g = 0; g < 2; ++g) {
            const int d0 = dg * 16 + g * 8;       // 8 consecutive d
            f16 hv[8], mv[8];
            #pragma unroll
            for (int j = 0; j < 8; ++j) {
                float zv = z[(size_t)(b * 256 + d0 + j) * 1024 + hw0 + q];
                float zh = 0.0f;
                if (fabsf(zv) >= F16_MIN_NORMAL) zh = (float)(f16)zv;
                hv[j] = (f16)zh;
                mv[j] = (f16)((zv - zh) * 2048.0f);
            }
            const int off = (q * 512 + d0 * 2) ^ ((q & 7) << 4);  // 16B-aligned
            *(f16x8*)(zsH + off) = *(const f16x8*)hv;
            *(f16x8*)(zsM + off) = *(const f16x8*)mv;
        }
    }

    float z2r[2][4];
    #pragma unroll
    for (int m = 0; m < 2; ++m)
        #pragma unroll
        for (int r = 0; r < 4; ++r)
            z2r[m][r] = z2w[nb + m * 16 + lg * 4 + r];

    float bestv[2][4];
    int   besti[2][4];
    #pragma unroll
    for (int m = 0; m < 2; ++m)
        #pragma unroll
        for (int r = 0; r < 4; ++r) { bestv[m][r] = INFINITY; besti[m][r] = 0; }

    // B register double-buffer: prefetch chunk 0 (before barrier; latency hides under z-build)
    f16x8 bhA[2], bmA[2], bhB[2], bmB[2];
    #pragma unroll
    for (int n = 0; n < 2; ++n) {
        bhA[n] = *(const f16x8*)(img + boff[n]);
        bmA[n] = *(const f16x8*)(img + 16384 + boff[n]);
    }

    __syncthreads();   // z planes published (drains lgkmcnt to 0)

    const uint32_t baseH = lds_a(zsH), baseM = lds_a(zsM);

    // A register double-buffer: prefetch ch 0 via asm reads -> 4 outstanding (invariant)
    f16x8 ahA[2], amA[2], ahB[2], amB[2];
    #pragma unroll
    for (int m = 0; m < 2; ++m) {
        ahA[m] = ds_read_b128_nowait(baseH + (uint32_t)aoffs[0][m]);
        amA[m] = ds_read_b128_nowait(baseM + (uint32_t)aoffs[0][m]);
    }

    // two accumulator sets (T15): group kt fills one while scores(kt-1) drain the other
    f32x4 accA1[2][2], accA2[2][2], accB1[2][2], accB2[2][2];
    float e2vA[2], e2vB[2];
    const f32x4 vzero = {0.0f, 0.0f, 0.0f, 0.0f};

// phase: issue B(t+1)->NXT B regs, issue A((ch+1)&7)->NXT A regs (asm, no wait), compute
// 2 deferred scores of kt-1, THEN s_waitcnt lgkmcnt(4) (drains only last phase's 4 reads)
// + sched_barrier fences around the MFMA cluster. Enter with 4 outstanding, issue 4,
// wait to 4 -> constant one-phase prefetch distance, enforced.
#define PHASE(KT, CH, AC1, AC2, CAH, CAM, NAH, NAM, CBH, CBM, NBH, NBM, PA1, PA2, PE2, DOSC) \
    {                                                                                      \
        const int t  = (KT) * 8 + (CH);                                                    \
        const int tn = (t + 1 < NCH) ? (t + 1) : 0;                                        \
        const char* nbase = img + (size_t)tn * CHB;                                        \
        _Pragma("unroll")                                                                  \
        for (int n = 0; n < 2; ++n) {                                                      \
            NBH[n] = *(const f16x8*)(nbase + boff[n]);                                     \
            NBM[n] = *(const f16x8*)(nbase + 16384 + boff[n]);                             \
        }                                                                                  \
        _Pragma("unroll")                                                                  \
        for (int m = 0; m < 2; ++m) {                                                      \
            NAH[m] = ds_read_b128_nowait(baseH + (uint32_t)aoffs[((CH) + 1) & 7][m]);      \
            NAM[m] = ds_read_b128_nowait(baseM + (uint32_t)aoffs[((CH) + 1) & 7][m]);      \
        }                                                                                  \
        if (DOSC) {                                                                        \
            _Pragma("unroll")                                                              \
            for (int it = 2 * (CH); it < 2 * (CH) + 2; ++it) {                             \
                const int m = it >> 3, n = (it >> 2) & 1, r = it & 3;                      \
                const int code = ((KT) - 1) * 256 + w * 32 + n * 16 + l15;                 \
                float rr = fmaf(PA2[m][n][r], 0x1p-11f, PA1[m][n][r]);                     \
                float tt = fmaf(rr, -0x1p-12f, z2r[m][r]);                                 \
                float s  = __fadd_rn(tt, PE2[n]);                                          \
                if (s < bestv[m][r]) { bestv[m][r] = s; besti[m][r] = code; }              \
            }                                                                              \
        }                                                                                  \
        asm volatile("s_waitcnt lgkmcnt(4)" ::: "memory");                                 \
        __builtin_amdgcn_sched_barrier(0);                                                 \
        __builtin_amdgcn_s_setprio(1);                                                     \
        _Pragma("unroll")                                                                  \
        for (int m = 0; m < 2; ++m)                                                        \
            _Pragma("unroll")                                                              \
            for (int n = 0; n < 2; ++n) {                                                  \
                AC1[m][n] = __builtin_amdgcn_mfma_f32_16x16x32_f16(CAH[m], CBH[n], AC1[m][n], 0, 0, 0); \
                AC2[m][n] = __builtin_amdgcn_mfma_f32_16x16x32_f16(CAH[m], CBM[n], AC2[m][n], 0, 0, 0); \
                AC2[m][n] = __builtin_amdgcn_mfma_f32_16x16x32_f16(CAM[m], CBH[n], AC2[m][n], 0, 0, 0); \
            }                                                                              \
        __builtin_amdgcn_s_setprio(0);                                                     \
        __builtin_amdgcn_sched_barrier(0);                                                 \
    }

// one k-tile group: zero acc, load e2v(kt), run 8 phases (2 deferred scores/phase if DOSC)
#define GROUP(KT, AC1, AC2, E2C, PA1, PA2, PE2, DOSC)                                      \
    {                                                                                      \
        _Pragma("unroll")                                                                  \
        for (int m = 0; m < 2; ++m)                                                        \
            _Pragma("unroll")                                                              \
            for (int n = 0; n < 2; ++n) { AC1[m][n] = vzero; AC2[m][n] = vzero; }          \
        _Pragma("unroll")                                                                  \
        for (int n = 0; n < 2; ++n)                                                        \
            E2C[n] = e2w[(KT) * 256 + w * 32 + n * 16 + l15];                              \
        PHASE(KT, 0, AC1, AC2, ahA, amA, ahB, amB, bhA, bmA, bhB, bmB, PA1, PA2, PE2, DOSC) \
        PHASE(KT, 1, AC1, AC2, ahB, amB, ahA, amA, bhB, bmB, bhA, bmA, PA1, PA2, PE2, DOSC) \
        PHASE(KT, 2, AC1, AC2, ahA, amA, ahB, amB, bhA, bmA, bhB, bmB, PA1, PA2, PE2, DOSC) \
        PHASE(KT, 3, AC1, AC2, ahB, amB, ahA, amA, bhB, bmB, bhA, bmA, PA1, PA2, PE2, DOSC) \
        PHASE(KT, 4, AC1, AC2, ahA, amA, ahB, amB, bhA, bmA, bhB, bmB, PA1, PA2, PE2, DOSC) \
        PHASE(KT, 5, AC1, AC2, ahB, amB, ahA, amA, bhB, bmB, bhA, bmA, PA1, PA2, PE2, DOSC) \
        PHASE(KT, 6, AC1, AC2, ahA, amA, ahB, amB, bhA, bmA, bhB, bmB, PA1, PA2, PE2, DOSC) \
        PHASE(KT, 7, AC1, AC2, ahB, amB, ahA, amA, bhB, bmB, bhA, bmA, PA1, PA2, PE2, DOSC) \
    }

    GROUP(0, accA1, accA2, e2vA, accB1, accB2, e2vB, 0)   // peel: no scores yet
    for (int ktp = 0; ktp < 15; ++ktp) {
        const int k1 = 2 * ktp + 1;
        GROUP(k1,     accB1, accB2, e2vB, accA1, accA2, e2vA, 1)  // scores kt=k1-1
        __builtin_amdgcn_s_barrier();                             // pacing every 2 kt
        GROUP(k1 + 1, accA1, accA2, e2vA, accB1, accB2, e2vB, 1)  // scores kt=k1
    }
    GROUP(31, accB1, accB2, e2vB, accA1, accA2, e2vA, 1)          // scores kt=30
    __builtin_amdgcn_s_barrier();
#undef PHASE
#undef GROUP

    // ---- tail: scores for kt=31 (same ops/order as the in-phase scores) ----
    #pragma unroll
    for (int m = 0; m < 2; ++m)
        #pragma unroll
        for (int n = 0; n < 2; ++n) {
            const int code = 31 * 256 + w * 32 + n * 16 + l15;
            #pragma unroll
            for (int r = 0; r < 4; ++r) {
                float rr = fmaf(accB2[m][n][r], 0x1p-11f, accB1[m][n][r]);
                float tt = fmaf(rr, -0x1p-12f, z2r[m][r]);
                float s  = __fadd_rn(tt, e2vB[n]);
                if (s < bestv[m][r]) { bestv[m][r] = s; besti[m][r] = code; }
            }
        }

    // ---- cross-lane argmin within each 16-lane column group ----
    #pragma unroll
    for (int m = 0; m < 2; ++m)
        #pragma unroll
        for (int r = 0; r < 4; ++r) {
            float v = bestv[m][r]; int idx = besti[m][r];
            #pragma unroll
            for (int dlt = 1; dlt < 16; dlt <<= 1) {
                float v2 = __shfl_xor(v, dlt, 64);
                int   i2 = __shfl_xor(idx, dlt, 64);
                if (v2 < v || (v2 == v && i2 < idx)) { v = v2; idx = i2; }
            }
            if (l15 == 0) {
                const int q = m * 16 + lg * 4 + r;   // 0..31
                redv[w][q] = v; redi[w][q] = idx;
            }
        }
    __syncthreads();
    if (tid < QT) {
        float bv = redv[0][tid]; int bi = redi[0][tid];
        #pragma unroll
        for (int ww = 1; ww < 8; ++ww) {
            float v = redv[ww][tid]; int ii = redi[ww][tid];
            if (v < bv || (v == bv && ii < bi)) { bv = v; bi = ii; }
        }
        bidx[tid] = bi;
        out1[nb + tid] = (float)bi;
    }
    __syncthreads();

    // ---- fused epilogue: quantized_st + commit-loss partial (float4 erow reads) ----
    {
        const int q = tid & 31, dg = tid >> 5;    // dg 0..15 -> 16 consecutive d
        const int myidx = bidx[q];
        const float* erow = emb + (size_t)myidx * 256;
        float lsum = 0.0f;
        #pragma unroll
        for (int g = 0; g < 4; ++g) {
            const int d0 = dg * 16 + g * 4;
            float4 qv4 = *(const float4*)(erow + d0);
            #pragma unroll
            for (int j = 0; j < 4; ++j) {
                const int d = d0 + j;
                const size_t gi = (size_t)(b * 256 + d) * 1024 + hw0 + q;
                float zv = z[gi];
                float qv = (&qv4.x)[j];
                out0[gi] = zv + (qv - zv);
                float e = zv - qv;
                lsum += e * e;
            }
        }
        #pragma unroll
        for (int off = 32; off > 0; off >>= 1) lsum += __shfl_down(lsum, off, 64);
        if (lane == 0) wsum[w] = lsum;
        __syncthreads();
        if (tid == 0) {
            float s = 0.0f;
            #pragma unroll
            for (int i = 0; i < 8; ++i) s += wsum[i];
            atomicAdd(loss_accum, s);
        }
    }
}

__global__ void loss_final(const float* __restrict__ loss_accum, float* __restrict__ out2) {
    out2[0] = loss_accum[0] * (1.0f / 4194304.0f);
}

extern "C" void kernel_launch(void* const* d_in, const int* in_sizes, int n_in,
                              void* d_out, int out_size, void* d_ws, size_t ws_size,
                              hipStream_t stream) {
    (void)in_sizes; (void)n_in; (void)out_size; (void)ws_size;
    const float* z   = (const float*)d_in[0];   // (16,256,32,32)
    const float* emb = (const float*)d_in[1];   // (8192,256)
    float* ws_f = (float*)d_ws;
    char*  wsb  = (char*)d_ws;
    float* loss = ws_f;                          // [0]
    float* e2   = ws_f + 64;                     // 8192 f32
    float* z2   = ws_f + 64 + KCODES;            // 16384 f32
    char*  img  = wsb + 131072;                  // 8 MB fp16-plane image
    float* out0 = (float*)d_out;                 // quantized_st: 4,194,304
    float* out1 = out0 + (size_t)4194304;        // indices:      16,384
    float* out2 = out1 + (size_t)16384;          // commit_loss:  1

    esplit_kernel<<<KCODES, 256, 0, stream>>>(emb, img, e2);
    z2_kernel<<<NTOT / 256, 256, 0, stream>>>(z, z2, loss);
    vq_main<<<NTOT / QT, 512, 0, stream>>>(z, emb, e2, z2, img, loss, out0, out1);
    loss_final<<<1, 1, 0, stream>>>(loss, out2);
}

// Round 20
// 215.267 us; speedup vs baseline: 1.0951x; 1.0951x over previous
//
#include <hip/hip_runtime.h>
#include <math.h>

typedef _Float16 f16;
typedef _Float16 f16x4 __attribute__((ext_vector_type(4)));
typedef _Float16 f16x8 __attribute__((ext_vector_type(8)));
typedef float f32x4 __attribute__((ext_vector_type(4)));

#define KCODES 8192
#define DDIM   256
#define NTOT   16384
#define QT     32      // queries per block; grid 512 = 2 lockstep generations at 1 block/CU
#define NKT    32      // k-tiles of 256 codes
#define NCH    256     // total 32KB chunks = NKT*8
#define CHB    32768   // chunk image bytes: 2 planes * 256 codes * 32 d * 2B

#define F16_MIN_NORMAL 6.103515625e-05f

// ws layout: [0] loss | +256B e2[8192] f32 | (z2 slot unused now) | +131072B emb-plane image (8 MB)

// split emb into 2 fp16 planes (pre-scaled by 2^13) as the swizzled image; fused e2.
// VECTORIZED: 4 rows/block, float4 loads, f16x4 (8B) stores. Per-element plane values
// bit-identical to rounds 3-19 (same __fmul_rn/cast sequence). e2 reduce order changed
// (per-thread 4-chunk then wave shfl) — e2 enters the score ~10x below half-ulp(tt), so
// its exact fp32 value is argmin-irrelevant. Also zeroes the loss accumulator.
__global__ void esplit_kernel(const float* __restrict__ emb, char* __restrict__ img,
                              float* __restrict__ e2out, float* __restrict__ loss) {
    const int c4 = blockIdx.x;          // rows 4*c4 .. 4*c4+3
    const int r  = threadIdx.x >> 6;    // 0..3 (one wave per row)
    const int cd = threadIdx.x & 63;    // d = cd*4 .. cd*4+3
    if (c4 == 0 && threadIdx.x == 0) loss[0] = 0.0f;
    const int c = c4 * 4 + r;
    float4 ev4 = *(const float4*)(emb + (size_t)c * 256 + cd * 4);
    double sq = 0.0;
    f16 hh[4], mm[4];
    #pragma unroll
    for (int j = 0; j < 4; ++j) {
        float ev = (&ev4.x)[j];
        sq += (double)__fmul_rn(ev, ev);
        float e = ev * 8192.0f;                             // exact pow2 scale
        float eh = 0.0f;
        if (fabsf(e) >= F16_MIN_NORMAL) eh = (float)(f16)e; // normal-or-zero hi plane
        hh[j] = (f16)eh;
        mm[j] = (f16)((e - eh) * 2048.0f);                  // residual scaled 2^11
    }
    #pragma unroll
    for (int off = 32; off > 0; off >>= 1) sq += __shfl_down(sq, off, 64);
    if (cd == 0) e2out[c] = (float)sq;
    const int kt = c >> 8, chb = cd >> 3, ci = c & 255, dp0 = (cd & 7) * 4;
    char* p = img + (size_t)(kt * 8 + chb) * CHB;
    const int off2 = (ci * 64 + dp0 * 2) ^ ((ci & 7) << 4); // XOR swizzle (bits 4-6);
    // 8B span stays contiguous under the XOR (all bytes share bits >=3)
    *(f16x4*)(p + off2) = *(const f16x4*)hh;
    *(f16x4*)(p + 16384 + off2) = *(const f16x4*)mm;
}

// EXACT R13 k-loop (QT=32, 8 waves, A+B register double-buffers, T15 score spreading).
// NEW vs R13: (1) z2 computed IN-KERNEL during z-build (fp64 partials -> LDS reduce) —
// removes the z2 kernel and its 64MB re-read of z; z2 summation order differs at the
// 1e-13 level, argmin-invariant (any accurate fp32 z2 shifts all d2[k] by grid multiples).
// (2) pacing barrier every 4 k-tiles via conditional branch (no unroll change).
__launch_bounds__(512, 2)
__global__ void vq_main(const float* __restrict__ z, const float* __restrict__ emb,
                        const float* __restrict__ e2w,
                        const char* __restrict__ img, float* __restrict__ loss_accum,
                        float* __restrict__ out0, float* __restrict__ out1) {
    // 41 KB per plane (first 16 KB = z planes; tails hold z2 scratch) -> 86 KB -> 1 block/CU
    __shared__ __align__(16) char zsH[41984];     // z hi plane  [32 q][256 d] f16, swizzled
    __shared__ __align__(16) char zsM[41984];     // z mid plane (scaled 2^11)
    __shared__ float redv[8][QT];
    __shared__ int   redi[8][QT];
    __shared__ int   bidx[QT];
    __shared__ float wsum[8];

    const int tid  = threadIdx.x;
    const int w    = tid >> 6;
    const int lane = tid & 63;
    const int l15  = lane & 15;
    const int lg   = lane >> 4;
    const int nb   = blockIdx.x * QT;
    const int b    = nb >> 10;
    const int hw0  = nb & 1023;

    // per-lane B read offsets (fixed per chunk; same formula as rounds 3-19)
    int boff[2];
    #pragma unroll
    for (int n = 0; n < 2; ++n) {
        const int c = w * 32 + n * 16 + l15;
        boff[n] = (c * 64 + lg * 16) ^ ((c & 7) << 4);
    }
    // precomputed A-LDS offsets per (ch, m)
    int aoffs[8][2];
    #pragma unroll
    for (int ch = 0; ch < 8; ++ch)
        #pragma unroll
        for (int m = 0; m < 2; ++m) {
            const int q = m * 16 + l15;
            aoffs[ch][m] = (q * 512 + (ch * 32 + lg * 8) * 2) ^ ((q & 7) << 4);
        }

    // ---- build z fp16 planes in LDS + fp64 z2 partials (plane values bit-identical) ----
    {
        const int q = tid & 31, dg = tid >> 5;    // dg 0..15 -> 16 consecutive d per thread
        double dacc = 0.0;
        #pragma unroll
        for (int g = 0; g < 2; ++g) {
            const int d0 = dg * 16 + g * 8;       // 8 consecutive d
            f16 hv[8], mv[8];
            #pragma unroll
            for (int j = 0; j < 8; ++j) {
                float zv = z[(size_t)(b * 256 + d0 + j) * 1024 + hw0 + q];
                dacc += (double)__fmul_rn(zv, zv);
                float zh = 0.0f;
                if (fabsf(zv) >= F16_MIN_NORMAL) zh = (float)(f16)zv;
                hv[j] = (f16)zh;
                mv[j] = (f16)((zv - zh) * 2048.0f);
            }
            const int off = (q * 512 + d0 * 2) ^ ((q & 7) << 4);  // 16B-aligned
            *(f16x8*)(zsH + off) = *(const f16x8*)hv;
            *(f16x8*)(zsM + off) = *(const f16x8*)mv;
        }
        ((double*)(zsH + 16384))[tid] = dacc;     // partials in zsH tail (4 KB)
    }

    float bestv[2][4];
    int   besti[2][4];
    #pragma unroll
    for (int m = 0; m < 2; ++m)
        #pragma unroll
        for (int r = 0; r < 4; ++r) { bestv[m][r] = INFINITY; besti[m][r] = 0; }

    // B register double-buffer: prefetch chunk 0 (latency hides under z-build/reduce)
    f16x8 bhA[2], bmA[2], bhB[2], bmB[2];
    #pragma unroll
    for (int n = 0; n < 2; ++n) {
        bhA[n] = *(const f16x8*)(img + boff[n]);
        bmA[n] = *(const f16x8*)(img + 16384 + boff[n]);
    }

    __syncthreads();   // z planes + partials published

    // z2 reduce: query q = sum of 16 per-thread partials, dg ascending (deterministic)
    if (tid < 32) {
        const double* zp = (const double*)(zsH + 16384);
        double s = 0.0;
        #pragma unroll
        for (int dg = 0; dg < 16; ++dg) s += zp[dg * 32 + tid];
        ((float*)(zsM + 16384))[tid] = (float)s;
    }
    __syncthreads();

    float z2r[2][4];
    {
        const float* z2s = (const float*)(zsM + 16384);
        #pragma unroll
        for (int m = 0; m < 2; ++m)
            #pragma unroll
            for (int r = 0; r < 4; ++r)
                z2r[m][r] = z2s[m * 16 + lg * 4 + r];
    }

    // A register double-buffer: prefetch ch 0 fragments
    f16x8 ahA[2], amA[2], ahB[2], amB[2];
    #pragma unroll
    for (int m = 0; m < 2; ++m) {
        ahA[m] = *(const f16x8*)(zsH + aoffs[0][m]);
        amA[m] = *(const f16x8*)(zsM + aoffs[0][m]);
    }

    // two accumulator sets (T15): group kt fills one while scores(kt-1) drain the other
    f32x4 accA1[2][2], accA2[2][2], accB1[2][2], accB2[2][2];
    float e2vA[2], e2vB[2];
    const f32x4 vzero = {0.0f, 0.0f, 0.0f, 0.0f};

// phase: issue B(t+1)->NXT B regs, issue A((ch+1)&7)->NXT A regs, optionally compute 2
// deferred scores (items 2*CH, 2*CH+1) of kt-1 from the OTHER acc set, then MFMA on CUR.
#define PHASE(KT, CH, AC1, AC2, CAH, CAM, NAH, NAM, CBH, CBM, NBH, NBM, PA1, PA2, PE2, DOSC) \
    {                                                                                      \
        const int t  = (KT) * 8 + (CH);                                                    \
        const int tn = (t + 1 < NCH) ? (t + 1) : 0;                                        \
        const char* nbase = img + (size_t)tn * CHB;                                        \
        _Pragma("unroll")                                                                  \
        for (int n = 0; n < 2; ++n) {                                                      \
            NBH[n] = *(const f16x8*)(nbase + boff[n]);                                     \
            NBM[n] = *(const f16x8*)(nbase + 16384 + boff[n]);                             \
        }                                                                                  \
        _Pragma("unroll")                                                                  \
        for (int m = 0; m < 2; ++m) {                                                      \
            NAH[m] = *(const f16x8*)(zsH + aoffs[((CH) + 1) & 7][m]);                      \
            NAM[m] = *(const f16x8*)(zsM + aoffs[((CH) + 1) & 7][m]);                      \
        }                                                                                  \
        if (DOSC) {                                                                        \
            _Pragma("unroll")                                                              \
            for (int it = 2 * (CH); it < 2 * (CH) + 2; ++it) {                             \
                const int m = it >> 3, n = (it >> 2) & 1, r = it & 3;                      \
                const int code = ((KT) - 1) * 256 + w * 32 + n * 16 + l15;                 \
                float rr = fmaf(PA2[m][n][r], 0x1p-11f, PA1[m][n][r]);                     \
                float tt = fmaf(rr, -0x1p-12f, z2r[m][r]);                                 \
                float s  = __fadd_rn(tt, PE2[n]);                                          \
                if (s < bestv[m][r]) { bestv[m][r] = s; besti[m][r] = code; }              \
            }                                                                              \
        }                                                                                  \
        __builtin_amdgcn_s_setprio(1);                                                     \
        _Pragma("unroll")                                                                  \
        for (int m = 0; m < 2; ++m)                                                        \
            _Pragma("unroll")                                                              \
            for (int n = 0; n < 2; ++n) {                                                  \
                AC1[m][n] = __builtin_amdgcn_mfma_f32_16x16x32_f16(CAH[m], CBH[n], AC1[m][n], 0, 0, 0); \
                AC2[m][n] = __builtin_amdgcn_mfma_f32_16x16x32_f16(CAH[m], CBM[n], AC2[m][n], 0, 0, 0); \
                AC2[m][n] = __builtin_amdgcn_mfma_f32_16x16x32_f16(CAM[m], CBH[n], AC2[m][n], 0, 0, 0); \
            }                                                                              \
        __builtin_amdgcn_s_setprio(0);                                                     \
    }

// one k-tile group: zero acc, load e2v(kt), run 8 phases (2 deferred scores/phase if DOSC)
#define GROUP(KT, AC1, AC2, E2C, PA1, PA2, PE2, DOSC)                                      \
    {                                                                                      \
        _Pragma("unroll")                                                                  \
        for (int m = 0; m < 2; ++m)                                                        \
            _Pragma("unroll")                                                              \
            for (int n = 0; n < 2; ++n) { AC1[m][n] = vzero; AC2[m][n] = vzero; }          \
        _Pragma("unroll")                                                                  \
        for (int n = 0; n < 2; ++n)                                                        \
            E2C[n] = e2w[(KT) * 256 + w * 32 + n * 16 + l15];                              \
        PHASE(KT, 0, AC1, AC2, ahA, amA, ahB, amB, bhA, bmA, bhB, bmB, PA1, PA2, PE2, DOSC) \
        PHASE(KT, 1, AC1, AC2, ahB, amB, ahA, amA, bhB, bmB, bhA, bmA, PA1, PA2, PE2, DOSC) \
        PHASE(KT, 2, AC1, AC2, ahA, amA, ahB, amB, bhA, bmA, bhB, bmB, PA1, PA2, PE2, DOSC) \
        PHASE(KT, 3, AC1, AC2, ahB, amB, ahA, amA, bhB, bmB, bhA, bmA, PA1, PA2, PE2, DOSC) \
        PHASE(KT, 4, AC1, AC2, ahA, amA, ahB, amB, bhA, bmA, bhB, bmB, PA1, PA2, PE2, DOSC) \
        PHASE(KT, 5, AC1, AC2, ahB, amB, ahA, amA, bhB, bmB, bhA, bmA, PA1, PA2, PE2, DOSC) \
        PHASE(KT, 6, AC1, AC2, ahA, amA, ahB, amB, bhA, bmA, bhB, bmB, PA1, PA2, PE2, DOSC) \
        PHASE(KT, 7, AC1, AC2, ahB, amB, ahA, amA, bhB, bmB, bhA, bmA, PA1, PA2, PE2, DOSC) \
    }

    GROUP(0, accA1, accA2, e2vA, accB1, accB2, e2vB, 0)   // peel: no scores yet
    for (int ktp = 0; ktp < 15; ++ktp) {
        const int k1 = 2 * ktp + 1;
        GROUP(k1,     accB1, accB2, e2vB, accA1, accA2, e2vA, 1)  // scores kt=k1-1
        if (ktp & 1) __builtin_amdgcn_s_barrier();                // pacing every 4 kt
        GROUP(k1 + 1, accA1, accA2, e2vA, accB1, accB2, e2vB, 1)  // scores kt=k1
    }
    GROUP(31, accB1, accB2, e2vB, accA1, accA2, e2vA, 1)          // scores kt=30
    __builtin_amdgcn_s_barrier();
#undef PHASE
#undef GROUP

    // ---- tail: scores for kt=31 (same ops/order as the in-phase scores) ----
    #pragma unroll
    for (int m = 0; m < 2; ++m)
        #pragma unroll
        for (int n = 0; n < 2; ++n) {
            const int code = 31 * 256 + w * 32 + n * 16 + l15;
            #pragma unroll
            for (int r = 0; r < 4; ++r) {
                float rr = fmaf(accB2[m][n][r], 0x1p-11f, accB1[m][n][r]);
                float tt = fmaf(rr, -0x1p-12f, z2r[m][r]);
                float s  = __fadd_rn(tt, e2vB[n]);
                if (s < bestv[m][r]) { bestv[m][r] = s; besti[m][r] = code; }
            }
        }

    // ---- cross-lane argmin within each 16-lane column group ----
    #pragma unroll
    for (int m = 0; m < 2; ++m)
        #pragma unroll
        for (int r = 0; r < 4; ++r) {
            float v = bestv[m][r]; int idx = besti[m][r];
            #pragma unroll
            for (int dlt = 1; dlt < 16; dlt <<= 1) {
                float v2 = __shfl_xor(v, dlt, 64);
                int   i2 = __shfl_xor(idx, dlt, 64);
                if (v2 < v || (v2 == v && i2 < idx)) { v = v2; idx = i2; }
            }
            if (l15 == 0) {
                const int q = m * 16 + lg * 4 + r;   // 0..31
                redv[w][q] = v; redi[w][q] = idx;
            }
        }
    __syncthreads();
    if (tid < QT) {
        float bv = redv[0][tid]; int bi = redi[0][tid];
        #pragma unroll
        for (int ww = 1; ww < 8; ++ww) {
            float v = redv[ww][tid]; int ii = redi[ww][tid];
            if (v < bv || (v == bv && ii < bi)) { bv = v; bi = ii; }
        }
        bidx[tid] = bi;
        out1[nb + tid] = (float)bi;
    }
    __syncthreads();

    // ---- fused epilogue: quantized_st + commit-loss partial (float4 erow reads) ----
    {
        const int q = tid & 31, dg = tid >> 5;    // dg 0..15 -> 16 consecutive d
        const int myidx = bidx[q];
        const float* erow = emb + (size_t)myidx * 256;
        float lsum = 0.0f;
        #pragma unroll
        for (int g = 0; g < 4; ++g) {
            const int d0 = dg * 16 + g * 4;
            float4 qv4 = *(const float4*)(erow + d0);
            #pragma unroll
            for (int j = 0; j < 4; ++j) {
                const int d = d0 + j;
                const size_t gi = (size_t)(b * 256 + d) * 1024 + hw0 + q;
                float zv = z[gi];
                float qv = (&qv4.x)[j];
                out0[gi] = zv + (qv - zv);
                float e = zv - qv;
                lsum += e * e;
            }
        }
        #pragma unroll
        for (int off = 32; off > 0; off >>= 1) lsum += __shfl_down(lsum, off, 64);
        if (lane == 0) wsum[w] = lsum;
        __syncthreads();
        if (tid == 0) {
            float s = 0.0f;
            #pragma unroll
            for (int i = 0; i < 8; ++i) s += wsum[i];
            atomicAdd(loss_accum, s);
        }
    }
}

__global__ void loss_final(const float* __restrict__ loss_accum, float* __restrict__ out2) {
    out2[0] = loss_accum[0] * (1.0f / 4194304.0f);
}

extern "C" void kernel_launch(void* const* d_in, const int* in_sizes, int n_in,
                              void* d_out, int out_size, void* d_ws, size_t ws_size,
                              hipStream_t stream) {
    (void)in_sizes; (void)n_in; (void)out_size; (void)ws_size;
    const float* z   = (const float*)d_in[0];   // (16,256,32,32)
    const float* emb = (const float*)d_in[1];   // (8192,256)
    float* ws_f = (float*)d_ws;
    char*  wsb  = (char*)d_ws;
    float* loss = ws_f;                          // [0]
    float* e2   = ws_f + 64;                     // 8192 f32
    char*  img  = wsb + 131072;                  // 8 MB fp16-plane image
    float* out0 = (float*)d_out;                 // quantized_st: 4,194,304
    float* out1 = out0 + (size_t)4194304;        // indices:      16,384
    float* out2 = out1 + (size_t)16384;          // commit_loss:  1

    esplit_kernel<<<KCODES / 4, 256, 0, stream>>>(emb, img, e2, loss);
    vq_main<<<NTOT / QT, 512, 0, stream>>>(z, emb, e2, img, loss, out0, out1);
    loss_final<<<1, 1, 0, stream>>>(loss, out2);
}